// Round 1
// baseline (3929.877 us; speedup 1.0000x reference)
//
#include <hip/hip_runtime.h>

typedef unsigned short u16;

// ---------- dtype helpers ----------
__device__ __forceinline__ float bf2f(u16 x){
  union { unsigned u; float f; } c; c.u = ((unsigned)x) << 16; return c.f;
}
__device__ __forceinline__ u16 f2bf(float f){
  union { float f; unsigned u; } c; c.f = f;
  unsigned u = c.u;
  return (u16)((u + 0x7FFFu + ((u >> 16) & 1u)) >> 16);
}

template<bool BF> struct In;
template<> struct In<false> {
  static __device__ __forceinline__ float ld(const void* p, long i){ return ((const float*)p)[i]; }
  static __device__ __forceinline__ float4 ld4(const void* p, long i){
    return *(const float4*)((const float*)p + i);
  }
};
template<> struct In<true> {
  static __device__ __forceinline__ float ld(const void* p, long i){ return bf2f(((const u16*)p)[i]); }
  static __device__ __forceinline__ float4 ld4(const void* p, long i){
    ushort4 v = *(const ushort4*)((const u16*)p + i);
    return make_float4(bf2f(v.x), bf2f(v.y), bf2f(v.z), bf2f(v.w));
  }
};

// ---------- dtype detector ----------
// bf16 data: nearly all u16s have exponent ~[117,129]. f32 data read as u16:
// odd halves are valid bf16 (~100%), even halves random (~16% pass) -> ~58%.
__global__ void k_detect(const void* feats, int* flag){
  if (blockIdx.x==0 && threadIdx.x==0){
    const u16* p = (const u16*)feats;
    int good = 0;
    for (int i=0;i<256;i++){
      u16 vv = p[i];
      int e = (vv>>7)&0xFF;
      if (vv==0u || (e>=100 && e<=140)) good++;
    }
    *flag = (good >= 208) ? 1 : 0;
  }
}

// ---------- cls token ----------
template<bool BF>
__global__ void k_cls(const int* flag, const void* cls, float* h){
  if ((*flag!=0)!=BF) return;
  int b = blockIdx.x, t = threadIdx.x;
  for (int c=t; c<512; c+=256)
    h[((long)b*8192+191)*512 + c] = In<BF>::ld(cls, c);
}

// ---------- big GEMM: 128x128 tile, 8x8 micro, BK=16 ----------
// MODE 0: fc1   A=feats(T)[16000,1024] B=fc1_w(T)[1024,512] -> relu(+bias), scatter into h rows b*8192+192+tok
// MODE 1: qkv   A=xln(f32)[16384,512]  B=qkv_w(T)[512,1536] -> split q/k/v head-major, q*=0.125
// MODE 2: proj  A=heads(f32, gathered) B=out_w(T)[512,512]  -> +bias, h += (rows pos>=191 only)
template<bool BF, int MODE>
__launch_bounds__(256)
__global__ void k_gemm(const int* flag, const void* A, const void* B, const void* bias,
                       float* hout, float* qo, float* ko, float* vo,
                       int M, int N, int K){
  if ((*flag!=0)!=BF) return;
  __shared__ float As[16][132];
  __shared__ float Bs[16][132];
  const int tid = threadIdx.x;
  const int m0 = blockIdx.x * 128, n0 = blockIdx.y * 128;
  const int tx = tid & 15, ty = tid >> 4;
  float acc[8][8];
  for (int i=0;i<8;i++) for (int j=0;j<8;j++) acc[i][j]=0.f;

  const int qA = (tid & 3) * 4;    // k-quad within tile
  const int mA = tid >> 2;         // 0..63
  const int kB = tid >> 4;         // 0..15
  const int nB = (tid & 15) * 8;

  for (int k0 = 0; k0 < K; k0 += 16){
    #pragma unroll
    for (int pass=0; pass<2; ++pass){
      int mr = mA + pass*64;
      int m  = m0 + mr;
      int kk = k0 + qA;
      float4 a;
      if constexpr (MODE == 2){
        int b = m >> 13, pos = m & 8191;
        int hh = kk >> 6, d = kk & 63;
        const float* hp = (const float*)A;
        a = *(const float4*)(hp + ((((long)(b*8+hh))*8192 + pos) << 6) + d);
      } else if constexpr (MODE == 1){
        a = *(const float4*)((const float*)A + (long)m*K + kk);
      } else {
        a = In<BF>::ld4(A, (long)m*K + kk);
      }
      As[qA+0][mr]=a.x; As[qA+1][mr]=a.y; As[qA+2][mr]=a.z; As[qA+3][mr]=a.w;
    }
    {
      long off = (long)(k0+kB)*N + n0 + nB;
      float4 b0 = In<BF>::ld4(B, off);
      float4 b1 = In<BF>::ld4(B, off+4);
      Bs[kB][nB+0]=b0.x; Bs[kB][nB+1]=b0.y; Bs[kB][nB+2]=b0.z; Bs[kB][nB+3]=b0.w;
      Bs[kB][nB+4]=b1.x; Bs[kB][nB+5]=b1.y; Bs[kB][nB+6]=b1.z; Bs[kB][nB+7]=b1.w;
    }
    __syncthreads();
    #pragma unroll
    for (int kk=0; kk<16; ++kk){
      float4 a0 = *(const float4*)&As[kk][ty*8];
      float4 a1 = *(const float4*)&As[kk][ty*8+4];
      float4 b0 = *(const float4*)&Bs[kk][tx*8];
      float4 b1 = *(const float4*)&Bs[kk][tx*8+4];
      float av[8] = {a0.x,a0.y,a0.z,a0.w,a1.x,a1.y,a1.z,a1.w};
      float bv[8] = {b0.x,b0.y,b0.z,b0.w,b1.x,b1.y,b1.z,b1.w};
      #pragma unroll
      for (int i=0;i<8;i++)
        #pragma unroll
        for (int j=0;j<8;j++) acc[i][j] += av[i]*bv[j];
    }
    __syncthreads();
  }

  if constexpr (MODE == 0){
    float bb[8];
    for (int j=0;j<8;j++) bb[j] = In<BF>::ld(bias, n0 + tx*8 + j);
    for (int i=0;i<8;i++){
      int r = m0 + ty*8 + i;
      int b = r / 8000;
      int tok = r - b*8000;
      float* dst = hout + ((long)(b*8192 + 192 + tok))*512 + n0 + tx*8;
      for (int j=0;j<8;j++) dst[j] = fmaxf(acc[i][j] + bb[j], 0.f);
    }
  } else if constexpr (MODE == 1){
    int c0 = n0 + tx*8;
    int which = c0 >> 9;
    int head  = (c0 >> 6) & 7;
    int d0    = c0 & 63;
    float* base = (which==0) ? qo : (which==1 ? ko : vo);
    float scale = (which==0) ? 0.125f : 1.0f;
    for (int i=0;i<8;i++){
      int r = m0 + ty*8 + i;
      int b = r >> 13, pos = r & 8191;
      float* dst = base + ((((long)(b*8+head))*8192 + pos) << 6) + d0;
      for (int j=0;j<8;j++) dst[j] = acc[i][j]*scale;
    }
  } else {
    float bb[8];
    int c0 = n0 + tx*8;
    for (int j=0;j<8;j++) bb[j] = In<BF>::ld(bias, c0 + j);
    for (int i=0;i<8;i++){
      int r = m0 + ty*8 + i;
      int pos = r & 8191;
      if (pos < 191) continue;      // out[:, -n:] slice: pad rows dropped
      float* dst = hout + (long)r*512 + c0;
      for (int j=0;j<8;j++) dst[j] += acc[i][j] + bb[j];
    }
  }
}

// ---------- layernorm (pad rows -> 0) ----------
template<bool BF>
__global__ void k_ln(const int* flag, const float* hsrc, const void* g, const void* bt, float* xln){
  if ((*flag!=0)!=BF) return;
  int row = blockIdx.x;          // 0..16383
  int pos = row & 8191;
  int t = threadIdx.x;
  long base = (long)row*512 + t*2;
  if (pos < 191){ xln[base]=0.f; xln[base+1]=0.f; return; }
  float2 x = *(const float2*)(hsrc + base);
  __shared__ float red[4];
  float s = x.x + x.y;
  for (int off=32; off; off>>=1) s += __shfl_down(s, off, 64);
  if ((t&63)==0) red[t>>6]=s;
  __syncthreads();
  float mean = (red[0]+red[1]+red[2]+red[3]) * (1.f/512.f);
  __syncthreads();
  float d0 = x.x-mean, d1 = x.y-mean;
  float ss = d0*d0 + d1*d1;
  for (int off=32; off; off>>=1) ss += __shfl_down(ss, off, 64);
  if ((t&63)==0) red[t>>6]=ss;
  __syncthreads();
  float rstd = rsqrtf((red[0]+red[1]+red[2]+red[3])*(1.f/512.f) + 1e-5f);
  xln[base]   = d0*rstd*In<BF>::ld(g,(long)t*2)   + In<BF>::ld(bt,(long)t*2);
  xln[base+1] = d1*rstd*In<BF>::ld(g,(long)t*2+1) + In<BF>::ld(bt,(long)t*2+1);
}

// ---------- landmark means (32 tokens per landmark) ----------
__global__ void k_landmark(const float* src, float* dst){
  int g = blockIdx.x, bh = blockIdx.y, d = threadIdx.x;   // 64 threads
  const float* p = src + (((long)bh*8192) + g*32)*64 + d;
  float s = 0.f;
  #pragma unroll
  for (int j=0;j<32;j++) s += p[j*64];
  dst[((long)bh*256 + g)*64 + d] = s*(1.f/32.f);
}

// ---------- a2 = softmax(q_l @ k_l^T) ----------
__launch_bounds__(256)
__global__ void k_a2(const float* qlm, const float* klm, float* a2){
  __shared__ float qls[16][68];
  __shared__ float kls[64][65];
  __shared__ float Sf[16][260];
  __shared__ float red[4];
  int bh = blockIdx.y, rt = blockIdx.x, t = threadIdx.x;
  const float* qp = qlm + ((long)bh*256 + rt*16)*64;
  { int fidx = t*4; int r = fidx>>6, c = fidx&63;
    float4 a = *(const float4*)(qp + fidx);
    qls[r][c]=a.x; qls[r][c+1]=a.y; qls[r][c+2]=a.z; qls[r][c+3]=a.w; }
  const float* kp = klm + (long)bh*16384;
  int cl = t & 63, ig = t >> 6;
  for (int kt=0; kt<4; ++kt){
    __syncthreads();
    for (int l=0;l<4;l++){
      int fidx = (l*256+t)*4; int r = fidx>>6, c = fidx&63;
      float4 a = *(const float4*)(kp + (long)(kt*64+r)*64 + c);
      kls[r][c]=a.x; kls[r][c+1]=a.y; kls[r][c+2]=a.z; kls[r][c+3]=a.w;
    }
    __syncthreads();
    float s0=0,s1=0,s2=0,s3=0;
    #pragma unroll
    for (int d=0;d<64;d++){
      float kv = kls[cl][d];
      s0 += qls[ig*4+0][d]*kv;
      s1 += qls[ig*4+1][d]*kv;
      s2 += qls[ig*4+2][d]*kv;
      s3 += qls[ig*4+3][d]*kv;
    }
    Sf[ig*4+0][kt*64+cl]=s0;
    Sf[ig*4+1][kt*64+cl]=s1;
    Sf[ig*4+2][kt*64+cl]=s2;
    Sf[ig*4+3][kt*64+cl]=s3;
  }
  __syncthreads();
  float* arow = a2 + ((long)bh*256 + rt*16)*256;
  for (int i=0;i<16;i++){
    float val = Sf[i][t];
    float m = val;
    for (int off=1; off<64; off<<=1) m = fmaxf(m, __shfl_xor(m,off,64));
    if ((t&63)==0) red[t>>6]=m;
    __syncthreads();
    m = fmaxf(fmaxf(red[0],red[1]),fmaxf(red[2],red[3]));
    __syncthreads();
    float e = __expf(val - m);
    float sum = e;
    for (int off=1; off<64; off<<=1) sum += __shfl_xor(sum,off,64);
    if ((t&63)==0) red[t>>6]=sum;
    __syncthreads();
    sum = red[0]+red[1]+red[2]+red[3];
    __syncthreads();
    arow[(long)i*256 + t] = e/sum;
  }
}

// ---------- pinv denominator: max col-sum * max row-sum (global over bh) ----------
__global__ void k_colrow(const float* a2, float* rc){
  int bh = blockIdx.x, t = threadIdx.x;
  const float* p = a2 + (long)bh*65536;
  float cs=0.f, rs=0.f;
  for (int r=0;r<256;r++) cs += fabsf(p[(long)r*256 + t]);
  for (int c=0;c<256;c++) rs += fabsf(p[(long)t*256 + c]);
  __shared__ float red[4];
  for (int off=32; off; off>>=1) cs = fmaxf(cs, __shfl_down(cs,off,64));
  if ((t&63)==0) red[t>>6]=cs;
  __syncthreads();
  if (t==0) rc[bh] = fmaxf(fmaxf(red[0],red[1]),fmaxf(red[2],red[3]));
  __syncthreads();
  for (int off=32; off; off>>=1) rs = fmaxf(rs, __shfl_down(rs,off,64));
  if ((t&63)==0) red[t>>6]=rs;
  __syncthreads();
  if (t==0) rc[16+bh] = fmaxf(fmaxf(red[0],red[1]),fmaxf(red[2],red[3]));
}
__global__ void k_denom(const float* rc, float* denom){
  float cm=0.f, rm=0.f;
  for (int i=0;i<16;i++){ cm=fmaxf(cm,rc[i]); rm=fmaxf(rm,rc[16+i]); }
  *denom = cm*rm;
}

// ---------- z0 = a2^T / denom ----------
__global__ void k_z0(const float* a2, const float* denom, float* z){
  __shared__ float tile[32][33];
  int bh = blockIdx.z;
  int c0 = blockIdx.x*32, r0 = blockIdx.y*32;
  int x = threadIdx.x & 31, y = threadIdx.x >> 5;  // y 0..7
  const float* p = a2 + (long)bh*65536;
  #pragma unroll
  for (int yy=0; yy<32; yy+=8) tile[y+yy][x] = p[(long)(r0+y+yy)*256 + c0 + x];
  __syncthreads();
  float inv = 1.0f / (*denom);
  float* zp = z + (long)bh*65536;
  #pragma unroll
  for (int yy=0; yy<32; yy+=8) zp[(long)(c0+y+yy)*256 + r0 + x] = tile[x][y+yy]*inv;
}

// ---------- batched 256-dim GEMM, 64x64 tile: C = s1*(A@B) + d1*I  (opt C2) ----------
__launch_bounds__(256)
__global__ void k_mm256(const float* A, const float* Bm, float* C, float* C2,
                        float d1, float s1, float d2, float s2, int N, int K){
  __shared__ float As[16][68];
  __shared__ float Bs[16][68];
  int bh = blockIdx.z;
  const float* Ap = A  + (long)bh*65536;
  const float* Bp = Bm + (long)bh*K*N;
  int tid = threadIdx.x;
  int m0 = blockIdx.x*64, n0 = blockIdx.y*64;
  int tx = tid & 15, ty = tid >> 4;
  float acc[4][4];
  for (int i=0;i<4;i++) for (int j=0;j<4;j++) acc[i][j]=0.f;
  int mA = tid >> 2, qA = (tid & 3)*4;
  int kB = tid >> 4, nB = (tid & 15)*4;
  for (int k0=0; k0<K; k0+=16){
    float4 a = *(const float4*)(Ap + (long)(m0+mA)*K + k0 + qA);
    As[qA+0][mA]=a.x; As[qA+1][mA]=a.y; As[qA+2][mA]=a.z; As[qA+3][mA]=a.w;
    float4 b = *(const float4*)(Bp + (long)(k0+kB)*N + n0 + nB);
    Bs[kB][nB+0]=b.x; Bs[kB][nB+1]=b.y; Bs[kB][nB+2]=b.z; Bs[kB][nB+3]=b.w;
    __syncthreads();
    #pragma unroll
    for (int kk=0; kk<16; ++kk){
      float4 av = *(const float4*)&As[kk][ty*4];
      float4 bv = *(const float4*)&Bs[kk][tx*4];
      float avv[4]={av.x,av.y,av.z,av.w}, bvv[4]={bv.x,bv.y,bv.z,bv.w};
      #pragma unroll
      for (int i=0;i<4;i++)
        #pragma unroll
        for (int j=0;j<4;j++) acc[i][j] += avv[i]*bvv[j];
    }
    __syncthreads();
  }
  long cb = (long)bh*256*N;
  for (int i=0;i<4;i++){
    int r = m0+ty*4+i;
    for (int j=0;j<4;j++){
      int c = n0+tx*4+j;
      float di = (r==c) ? 1.f : 0.f;
      C[cb + (long)r*N + c] = s1*acc[i][j] + di*d1;
      if (C2) C2[cb + (long)r*N + c] = s2*acc[i][j] + di*d2;
    }
  }
}

// ---------- generic flash: O = softmax_rows(Q @ K^T) @ V ----------
// 16 query rows per block; K/V streamed in 64-row tiles via LDS. dh=64.
__launch_bounds__(256)
__global__ void k_flash(const float* Q, const float* Km, const float* Vm, float* O,
                        int kvlen, long qbs, long kvbs){
  __shared__ float qs[16][68];
  __shared__ float ks[64][68];
  __shared__ float vs[64][68];
  __shared__ float Ss[16][68];
  __shared__ float sc[16], lsh[16];
  int bh = blockIdx.y, qt = blockIdx.x, t = threadIdx.x;
  const float* qp = Q + (long)bh*qbs + (long)qt*16*64;
  { int fidx = t*4; int r = fidx>>6, c = fidx&63;
    float4 a = *(const float4*)(qp + fidx);
    qs[r][c]=a.x; qs[r][c+1]=a.y; qs[r][c+2]=a.z; qs[r][c+3]=a.w; }
  int j = t & 15, pq = t >> 4;     // scores: col group; PV: dim group
  float m_j = -1e30f, l_j = 0.f;   // valid in threads t<16
  float o0=0,o1=0,o2=0,o3=0;
  const float* kp = Km + (long)bh*kvbs;
  const float* vp = Vm + (long)bh*kvbs;
  for (int p0=0; p0<kvlen; p0+=64){
    __syncthreads();
    for (int l=0;l<4;l++){
      int fidx = (l*256 + t)*4; int r = fidx>>6, c = fidx&63;
      float4 a = *(const float4*)(kp + (long)(p0+r)*64 + c);
      ks[r][c]=a.x; ks[r][c+1]=a.y; ks[r][c+2]=a.z; ks[r][c+3]=a.w;
      float4 b = *(const float4*)(vp + (long)(p0+r)*64 + c);
      vs[r][c]=b.x; vs[r][c+1]=b.y; vs[r][c+2]=b.z; vs[r][c+3]=b.w;
    }
    __syncthreads();
    float s0=0,s1=0,s2=0,s3=0;
    #pragma unroll
    for (int d=0;d<64;d++){
      float qv = qs[j][d];
      s0 += qv*ks[pq*4+0][d];
      s1 += qv*ks[pq*4+1][d];
      s2 += qv*ks[pq*4+2][d];
      s3 += qv*ks[pq*4+3][d];
    }
    Ss[j][pq*4+0]=s0; Ss[j][pq*4+1]=s1; Ss[j][pq*4+2]=s2; Ss[j][pq*4+3]=s3;
    __syncthreads();
    if (t < 16){
      float m = m_j;
      #pragma unroll
      for (int p=0;p<64;p++) m = fmaxf(m, Ss[t][p]);
      float scale = __expf(m_j - m);
      float sum = l_j*scale;
      for (int p=0;p<64;p++){ float e = __expf(Ss[t][p]-m); Ss[t][p]=e; sum+=e; }
      m_j = m; l_j = sum; sc[t] = scale;
    }
    __syncthreads();
    float scl = sc[j];
    o0*=scl; o1*=scl; o2*=scl; o3*=scl;
    #pragma unroll
    for (int p=0;p<64;p++){
      float pv = Ss[j][p];
      o0 += pv*vs[p][pq*4+0];
      o1 += pv*vs[p][pq*4+1];
      o2 += pv*vs[p][pq*4+2];
      o3 += pv*vs[p][pq*4+3];
    }
  }
  if (t<16) lsh[t]=l_j;
  __syncthreads();
  float invl = 1.f/lsh[j];
  float* op = O + (long)bh*qbs + ((long)qt*16 + j)*64 + pq*4;
  op[0]=o0*invl; op[1]=o1*invl; op[2]=o2*invl; op[3]=o3*invl;
}

// ---------- depthwise conv residual over sequence (K=33), heads += res ----------
template<bool BF>
__launch_bounds__(256)
__global__ void k_conv(const int* flag, const float* v, const void* cw, float* heads){
  if ((*flag!=0)!=BF) return;
  __shared__ float vsl[160][64];
  __shared__ float cws[33];
  int bh = blockIdx.y, pt = blockIdx.x, t = threadIdx.x;
  int hh = bh & 7;
  if (t < 33) cws[t] = In<BF>::ld(cw, hh*33 + t);
  int p0 = pt*128;
  const float* vp = v + (long)bh*8192*64;
  for (int l=0;l<10;l++){
    int fidx = (l*256 + t)*4;
    int r = fidx>>6, c = fidx&63;
    int gp = p0 - 16 + r;
    if (gp>=0 && gp<8192){
      float4 a = *(const float4*)(vp + (long)gp*64 + c);
      vsl[r][c]=a.x; vsl[r][c+1]=a.y; vsl[r][c+2]=a.z; vsl[r][c+3]=a.w;
    } else {
      vsl[r][c]=0.f; vsl[r][c+1]=0.f; vsl[r][c+2]=0.f; vsl[r][c+3]=0.f;
    }
  }
  __syncthreads();
  int d = t & 63, pg = t >> 6;
  float* hp = heads + ((long)bh*8192 + p0)*64;
  for (int pp=0; pp<32; pp++){
    int pl = pp*4 + pg;
    float acc = 0.f;
    #pragma unroll
    for (int tt=0; tt<33; tt++) acc += vsl[pl+tt][d]*cws[tt];
    hp[(long)pl*64 + d] += acc;
  }
}

// ---------- final: LN(row cls) @ fc2 + softmax + argmax ----------
template<bool BF>
__global__ void k_final(const int* flag, const float* hbuf, const void* g, const void* bt,
                        const void* fw, const void* fb, void* outp){
  if ((*flag!=0)!=BF) return;
  int b = blockIdx.x, t = threadIdx.x;
  __shared__ float red[4];
  __shared__ float sx[512];
  __shared__ float lg[4];
  const float* x = hbuf + ((long)b*8192+191)*512;
  float2 xv = *(const float2*)(x + t*2);
  float s = xv.x + xv.y;
  for (int off=32; off; off>>=1) s += __shfl_down(s,off,64);
  if ((t&63)==0) red[t>>6]=s;
  __syncthreads();
  float mean = (red[0]+red[1]+red[2]+red[3])*(1.f/512.f);
  __syncthreads();
  float d0 = xv.x-mean, d1 = xv.y-mean;
  float ssq = d0*d0 + d1*d1;
  for (int off=32; off; off>>=1) ssq += __shfl_down(ssq,off,64);
  if ((t&63)==0) red[t>>6]=ssq;
  __syncthreads();
  float rstd = rsqrtf((red[0]+red[1]+red[2]+red[3])*(1.f/512.f) + 1e-5f);
  sx[t*2]   = d0*rstd*In<BF>::ld(g,(long)t*2)   + In<BF>::ld(bt,(long)t*2);
  sx[t*2+1] = d1*rstd*In<BF>::ld(g,(long)t*2+1) + In<BF>::ld(bt,(long)t*2+1);
  __syncthreads();
  int c = t>>7, jj = t&127;
  float part = 0.f;
  for (int kk=jj; kk<512; kk+=128) part += sx[kk]*In<BF>::ld(fw, (long)kk*2 + c);
  for (int off=1; off<64; off<<=1) part += __shfl_xor(part,off,64);
  if ((t&63)==0) lg[t>>6]=part;
  __syncthreads();
  if (t==0){
    float l0 = lg[0]+lg[1] + In<BF>::ld(fb,0);
    float l1 = lg[2]+lg[3] + In<BF>::ld(fb,1);
    float m = fmaxf(l0,l1);
    float e0 = __expf(l0-m), e1 = __expf(l1-m);
    float inv = 1.f/(e0+e1);
    float yh = (l1>l0) ? 1.f : 0.f;
    if (BF){
      u16* o = (u16*)outp;
      o[b*2+0]=f2bf(l0); o[b*2+1]=f2bf(l1);
      o[4+b*2+0]=f2bf(e0*inv); o[4+b*2+1]=f2bf(e1*inv);
      o[8+b]=f2bf(yh);
    } else {
      float* o = (float*)outp;
      o[b*2+0]=l0; o[b*2+1]=l1;
      o[4+b*2+0]=e0*inv; o[4+b*2+1]=e1*inv;
      o[8+b]=yh;
    }
  }
}

// ===================== host launch =====================
extern "C" void kernel_launch(void* const* d_in, const int* in_sizes, int n_in,
                              void* d_out, int out_size, void* d_ws, size_t ws_size,
                              hipStream_t stream){
  (void)in_sizes; (void)n_in; (void)out_size; (void)ws_size;
  const long TOKBUF = (long)2*8192*512;   // 8,388,608
  float* W    = (float*)d_ws;
  int*   flag = (int*)W;
  float* h    = W + 16;
  float* xln  = h   + TOKBUF;
  float* q    = xln + TOKBUF;
  float* k    = q   + TOKBUF;
  float* v    = k   + TOKBUF;
  float* heads= xln;                      // alias: xln dead after qkv GEMM
  float* ql   = v   + TOKBUF;
  float* kl   = ql  + 16L*256*64;
  float* w3   = kl  + 16L*256*64;
  float* zw   = w3  + 16L*256*64;
  float* a2   = zw  + 16L*256*64;
  float* z    = a2  + 16L*256*256;
  float* z2   = z   + 16L*256*256;
  float* xz   = z2  + 16L*256*256;
  float* t1   = xz  + 16L*256*256;
  float* t2   = t1  + 16L*256*256;
  float* rc   = t2  + 16L*256*256;        // 33 floats used

  dim3 B256(256);

  k_detect<<<dim3(1), dim3(64), 0, stream>>>(d_in[0], flag);

  k_cls<false><<<dim3(2), B256, 0, stream>>>(flag, d_in[3], h);
  k_cls<true ><<<dim3(2), B256, 0, stream>>>(flag, d_in[3], h);

  // fc1 + relu -> h rows 192..8191 per batch
  k_gemm<false,0><<<dim3(125,4), B256, 0, stream>>>(flag, d_in[0], d_in[1], d_in[2], h, nullptr,nullptr,nullptr, 16000,512,1024);
  k_gemm<true ,0><<<dim3(125,4), B256, 0, stream>>>(flag, d_in[0], d_in[1], d_in[2], h, nullptr,nullptr,nullptr, 16000,512,1024);

  for (int blk=0; blk<2; ++blk){
    const void* lng  = d_in[blk?10:4];
    const void* lnb  = d_in[blk?11:5];
    const void* qkvw = d_in[blk?12:6];
    const void* outw = d_in[blk?13:7];
    const void* outb = d_in[blk?14:8];
    const void* cw   = d_in[blk?15:9];

    k_ln<false><<<dim3(16384), B256, 0, stream>>>(flag, h, lng, lnb, xln);
    k_ln<true ><<<dim3(16384), B256, 0, stream>>>(flag, h, lng, lnb, xln);

    k_gemm<false,1><<<dim3(128,12), B256, 0, stream>>>(flag, xln, qkvw, nullptr, nullptr, q,k,v, 16384,1536,512);
    k_gemm<true ,1><<<dim3(128,12), B256, 0, stream>>>(flag, xln, qkvw, nullptr, nullptr, q,k,v, 16384,1536,512);

    k_landmark<<<dim3(256,16), dim3(64), 0, stream>>>(q, ql);
    k_landmark<<<dim3(256,16), dim3(64), 0, stream>>>(k, kl);

    k_a2<<<dim3(16,16), B256, 0, stream>>>(ql, kl, a2);
    k_colrow<<<dim3(16), B256, 0, stream>>>(a2, rc);
    k_denom<<<dim3(1), dim3(1), 0, stream>>>(rc, rc+32);
    k_z0<<<dim3(8,8,16), B256, 0, stream>>>(a2, rc+32, z);

    for (int it=0; it<6; ++it){
      float* zin  = (it&1) ? z2 : z;
      float* zout = (it&1) ? z  : z2;
      k_mm256<<<dim3(4,4,16), B256, 0, stream>>>(a2, zin, xz, t1, 0.f,1.f,  7.f,-1.f, 256,256);
      k_mm256<<<dim3(4,4,16), B256, 0, stream>>>(xz, t1, t2, nullptr, 15.f,-1.f, 0.f,0.f, 256,256);
      k_mm256<<<dim3(4,4,16), B256, 0, stream>>>(xz, t2, t1, nullptr, 13.f,-1.f, 0.f,0.f, 256,256);
      k_mm256<<<dim3(4,4,16), B256, 0, stream>>>(zin, t1, zout, nullptr, 0.f,0.25f, 0.f,0.f, 256,256);
    }
    // after 6 iters (even), result is in z

    // w3 = softmax(q_l @ k^T) @ v    [bh,256,64]
    k_flash<<<dim3(16,16), B256, 0, stream>>>(ql, k, v, w3, 8192, 16384L, 524288L);
    // zw = z @ w3                    [bh,256,64]
    k_mm256<<<dim3(4,1,16), B256, 0, stream>>>(z, w3, zw, nullptr, 0.f,1.f, 0.f,0.f, 64,256);
    // heads = softmax(q @ k_l^T) @ zw  [bh,8192,64]
    k_flash<<<dim3(512,16), B256, 0, stream>>>(q, kl, zw, heads, 256, 524288L, 16384L);

    k_conv<false><<<dim3(64,16), B256, 0, stream>>>(flag, v, cw, heads);
    k_conv<true ><<<dim3(64,16), B256, 0, stream>>>(flag, v, cw, heads);

    k_gemm<false,2><<<dim3(128,4), B256, 0, stream>>>(flag, heads, outw, outb, h, nullptr,nullptr,nullptr, 16384,512,512);
    k_gemm<true ,2><<<dim3(128,4), B256, 0, stream>>>(flag, heads, outw, outb, h, nullptr,nullptr,nullptr, 16384,512,512);
  }

  k_final<false><<<dim3(2), B256, 0, stream>>>(flag, h, d_in[16], d_in[17], d_in[18], d_in[19], d_out);
  k_final<true ><<<dim3(2), B256, 0, stream>>>(flag, h, d_in[16], d_in[17], d_in[18], d_in[19], d_out);
}

// Round 2
// 2790.839 us; speedup vs baseline: 1.4081x; 1.4081x over previous
//
#include <hip/hip_runtime.h>

typedef unsigned short u16;
typedef __attribute__((ext_vector_type(8))) short short8;
typedef __attribute__((ext_vector_type(4))) float f32x4;

__device__ __forceinline__ float bf2f(u16 x){
  union { unsigned u; float f; } c; c.u = ((unsigned)x) << 16; return c.f;
}
__device__ __forceinline__ u16 f2bf(float f){
  union { float f; unsigned u; } c; c.f = f;
  unsigned u = c.u;
  return (u16)((u + 0x7FFFu + ((u >> 16) & 1u)) >> 16);
}

__device__ __forceinline__ void gload16(const void* g, void* l){
  __builtin_amdgcn_global_load_lds(
    (const __attribute__((address_space(1))) void*)g,
    (__attribute__((address_space(3))) void*)l, 16, 0, 0);
}

// ---------- cls token ----------
__global__ void k_cls(const float* cls, float* h){
  int b = blockIdx.x, t = threadIdx.x;
  for (int c=t; c<512; c+=256)
    h[((long)b*8192+191)*512 + c] = cls[c];
}

// ---------- weight convert + transpose: W f32 [K][N] -> wT bf16 [N][K] ----------
__global__ void k_cvtT(const float* Wm, u16* wT, int K, int N){
  __shared__ float tile[32][33];
  int n0 = blockIdx.x*32, k0 = blockIdx.y*32;
  int x = threadIdx.x & 31, y = threadIdx.x >> 5;
  #pragma unroll
  for (int p=0;p<4;p++) tile[y+8*p][x] = Wm[(long)(k0+y+8*p)*N + n0 + x];
  __syncthreads();
  #pragma unroll
  for (int p=0;p<4;p++) wT[(long)(n0+y+8*p)*K + k0 + x] = f2bf(tile[x][y+8*p]);
}

// ---------- MFMA GEMM: 128x128 tile, BK=32, 4 waves, bf16 inputs f32 acc ----------
// MODE 0: fc1  A=feats f32 (reg-staged cvt), relu(+bias) scatter into h
// MODE 1: qkv  A=xln_bf,  split q/k/v head-major f32, q*=0.125
// MODE 2: proj A=heads_bf (gathered via per-lane addr), +bias, h += (pos>=191)
template<int MODE>
__launch_bounds__(256)
__global__ void k_gemm(const void* Av, const u16* Bt, const float* bias,
                       float* hout, float* qo, float* ko, float* vo,
                       int M, int N, int K){
  __shared__ __align__(16) u16 As[128*32];
  __shared__ __align__(16) u16 Bs[128*32];
  const int tid = threadIdx.x;
  const int wave = tid>>6, lane = tid&63;
  const int m0 = blockIdx.x*128, n0 = blockIdx.y*128;
  const int wr = wave>>1, wc = wave&1;
  f32x4 acc[4][4];
  #pragma unroll
  for (int i=0;i<4;i++)
    #pragma unroll
    for (int j=0;j<4;j++) acc[i][j] = (f32x4){0.f,0.f,0.f,0.f};

  for (int k0=0; k0<K; k0+=32){
    // ---- stage A ----
    if constexpr (MODE == 0){
      int r = tid>>1, half = tid&1;
      const float* gp = (const float*)Av + (long)(m0+r)*K + k0 + half*16;
      float4 f0 = *(const float4*)(gp+0);
      float4 f1 = *(const float4*)(gp+4);
      float4 f2 = *(const float4*)(gp+8);
      float4 f3 = *(const float4*)(gp+12);
      uint4 pa, pb;
      pa.x = f2bf(f0.x) | ((unsigned)f2bf(f0.y)<<16);
      pa.y = f2bf(f0.z) | ((unsigned)f2bf(f0.w)<<16);
      pa.z = f2bf(f1.x) | ((unsigned)f2bf(f1.y)<<16);
      pa.w = f2bf(f1.z) | ((unsigned)f2bf(f1.w)<<16);
      pb.x = f2bf(f2.x) | ((unsigned)f2bf(f2.y)<<16);
      pb.y = f2bf(f2.z) | ((unsigned)f2bf(f2.w)<<16);
      pb.z = f2bf(f3.x) | ((unsigned)f2bf(f3.y)<<16);
      pb.w = f2bf(f3.z) | ((unsigned)f2bf(f3.w)<<16);
      uint4* dst = (uint4*)&As[r*32 + half*16];
      dst[0] = pa; dst[1] = pb;
    } else {
      #pragma unroll
      for (int ci=0; ci<2; ++ci){
        int c = wave*2 + ci;
        int r = (c<<4) + (lane>>2), kq = lane&3;
        const u16* gp;
        if constexpr (MODE == 1){
          gp = (const u16*)Av + (long)(m0+r)*K + k0 + kq*8;
        } else {
          int rr = m0 + r; int b = rr>>13, pos = rr&8191;
          int cc = k0 + kq*8; int hh = cc>>6, d = cc&63;
          gp = (const u16*)Av + ((long)(b*8+hh)*8192 + pos)*64 + d;
        }
        gload16(gp, &As[c*512]);
      }
    }
    // ---- stage B (wT bf16 [N][K]) ----
    #pragma unroll
    for (int ci=0; ci<2; ++ci){
      int c = wave*2 + ci;
      int r = (c<<4) + (lane>>2), kq = lane&3;
      gload16(Bt + (long)(n0+r)*K + k0 + kq*8, &Bs[c*512]);
    }
    __syncthreads();
    short8 af[4], bf[4];
    int arow = wr*64 + (lane&15);
    int brow = wc*64 + (lane&15);
    int koff = (lane>>4)*8;
    #pragma unroll
    for (int i=0;i<4;i++){
      af[i] = *(const short8*)&As[(arow + i*16)*32 + koff];
      bf[i] = *(const short8*)&Bs[(brow + i*16)*32 + koff];
    }
    #pragma unroll
    for (int i=0;i<4;i++)
      #pragma unroll
      for (int j=0;j<4;j++)
        acc[i][j] = __builtin_amdgcn_mfma_f32_16x16x32_bf16(af[i], bf[j], acc[i][j], 0,0,0);
    __syncthreads();
  }

  const int lr = lane>>4, lc = lane&15;
  if constexpr (MODE == 0){
    #pragma unroll
    for (int j=0;j<4;j++){
      int cb = n0 + wc*64 + j*16 + lc;
      float bb = bias[cb];
      #pragma unroll
      for (int i=0;i<4;i++){
        #pragma unroll
        for (int r=0;r<4;r++){
          int row = m0 + wr*64 + i*16 + lr*4 + r;
          int b = (row >= 8000) ? 1 : 0;
          int tok = row - b*8000;
          hout[((long)(b*8192 + 192 + tok))*512 + cb] = fmaxf(acc[i][j][r] + bb, 0.f);
        }
      }
    }
  } else if constexpr (MODE == 1){
    #pragma unroll
    for (int j=0;j<4;j++){
      int cb = n0 + wc*64 + j*16 + lc;
      int which = cb>>9, head = (cb>>6)&7, d = cb&63;
      float* base = (which==0) ? qo : (which==1 ? ko : vo);
      float scale = (which==0) ? 0.125f : 1.0f;
      #pragma unroll
      for (int i=0;i<4;i++){
        #pragma unroll
        for (int r=0;r<4;r++){
          int row = m0 + wr*64 + i*16 + lr*4 + r;
          int b = row>>13, pos = row&8191;
          base[((long)(b*8+head)*8192 + pos)*64 + d] = acc[i][j][r]*scale;
        }
      }
    }
  } else {
    #pragma unroll
    for (int j=0;j<4;j++){
      int cb = n0 + wc*64 + j*16 + lc;
      float bb = bias[cb];
      #pragma unroll
      for (int i=0;i<4;i++){
        #pragma unroll
        for (int r=0;r<4;r++){
          int row = m0 + wr*64 + i*16 + lr*4 + r;
          int pos = row&8191;
          if (pos >= 191) hout[(long)row*512 + cb] += acc[i][j][r] + bb;
        }
      }
    }
  }
}

// ---------- layernorm: h f32 -> xln bf16 (pad rows -> 0) ----------
__global__ void k_ln(const float* hsrc, const float* g, const float* bt, u16* xlnb){
  int row = blockIdx.x;
  int pos = row & 8191;
  int t = threadIdx.x;
  long base = (long)row*512 + t*2;
  if (pos < 191){ *(unsigned*)&xlnb[base] = 0u; return; }
  float2 x = *(const float2*)(hsrc + base);
  __shared__ float red[4];
  float s = x.x + x.y;
  for (int off=32; off; off>>=1) s += __shfl_down(s, off, 64);
  if ((t&63)==0) red[t>>6]=s;
  __syncthreads();
  float mean = (red[0]+red[1]+red[2]+red[3]) * (1.f/512.f);
  __syncthreads();
  float d0 = x.x-mean, d1 = x.y-mean;
  float ss = d0*d0 + d1*d1;
  for (int off=32; off; off>>=1) ss += __shfl_down(ss, off, 64);
  if ((t&63)==0) red[t>>6]=ss;
  __syncthreads();
  float rstd = rsqrtf((red[0]+red[1]+red[2]+red[3])*(1.f/512.f) + 1e-5f);
  float o0 = d0*rstd*g[t*2]   + bt[t*2];
  float o1 = d1*rstd*g[t*2+1] + bt[t*2+1];
  *(unsigned*)&xlnb[base] = f2bf(o0) | ((unsigned)f2bf(o1)<<16);
}

// ---------- landmark means ----------
__global__ void k_landmark(const float* src, float* dst){
  int g = blockIdx.x, bh = blockIdx.y, d = threadIdx.x;
  const float* p = src + (((long)bh*8192) + g*32)*64 + d;
  float s = 0.f;
  #pragma unroll
  for (int j=0;j<32;j++) s += p[j*64];
  dst[((long)bh*256 + g)*64 + d] = s*(1.f/32.f);
}

// ---------- a2 = softmax(q_l @ k_l^T) ----------
__launch_bounds__(256)
__global__ void k_a2(const float* qlm, const float* klm, float* a2){
  __shared__ float qls[16][68];
  __shared__ float kls[64][65];
  __shared__ float Sf[16][260];
  __shared__ float red[4];
  int bh = blockIdx.y, rt = blockIdx.x, t = threadIdx.x;
  const float* qp = qlm + ((long)bh*256 + rt*16)*64;
  { int fidx = t*4; int r = fidx>>6, c = fidx&63;
    float4 a = *(const float4*)(qp + fidx);
    qls[r][c]=a.x; qls[r][c+1]=a.y; qls[r][c+2]=a.z; qls[r][c+3]=a.w; }
  const float* kp = klm + (long)bh*16384;
  int cl = t & 63, ig = t >> 6;
  for (int kt=0; kt<4; ++kt){
    __syncthreads();
    for (int l=0;l<4;l++){
      int fidx = (l*256+t)*4; int r = fidx>>6, c = fidx&63;
      float4 a = *(const float4*)(kp + (long)(kt*64+r)*64 + c);
      kls[r][c]=a.x; kls[r][c+1]=a.y; kls[r][c+2]=a.z; kls[r][c+3]=a.w;
    }
    __syncthreads();
    float s0=0,s1=0,s2=0,s3=0;
    #pragma unroll
    for (int d=0;d<64;d++){
      float kv = kls[cl][d];
      s0 += qls[ig*4+0][d]*kv;
      s1 += qls[ig*4+1][d]*kv;
      s2 += qls[ig*4+2][d]*kv;
      s3 += qls[ig*4+3][d]*kv;
    }
    Sf[ig*4+0][kt*64+cl]=s0;
    Sf[ig*4+1][kt*64+cl]=s1;
    Sf[ig*4+2][kt*64+cl]=s2;
    Sf[ig*4+3][kt*64+cl]=s3;
  }
  __syncthreads();
  float* arow = a2 + ((long)bh*256 + rt*16)*256;
  for (int i=0;i<16;i++){
    float val = Sf[i][t];
    float m = val;
    for (int off=1; off<64; off<<=1) m = fmaxf(m, __shfl_xor(m,off,64));
    if ((t&63)==0) red[t>>6]=m;
    __syncthreads();
    m = fmaxf(fmaxf(red[0],red[1]),fmaxf(red[2],red[3]));
    __syncthreads();
    float e = __expf(val - m);
    float sum = e;
    for (int off=1; off<64; off<<=1) sum += __shfl_xor(sum,off,64);
    if ((t&63)==0) red[t>>6]=sum;
    __syncthreads();
    sum = red[0]+red[1]+red[2]+red[3];
    __syncthreads();
    arow[(long)i*256 + t] = e/sum;
  }
}

// ---------- pinv denominator ----------
__global__ void k_colrow(const float* a2, float* rc){
  int bh = blockIdx.x, t = threadIdx.x;
  const float* p = a2 + (long)bh*65536;
  float cs=0.f, rs=0.f;
  for (int r=0;r<256;r++) cs += fabsf(p[(long)r*256 + t]);
  for (int c=0;c<256;c++) rs += fabsf(p[(long)t*256 + c]);
  __shared__ float red[4];
  for (int off=32; off; off>>=1) cs = fmaxf(cs, __shfl_down(cs,off,64));
  if ((t&63)==0) red[t>>6]=cs;
  __syncthreads();
  if (t==0) rc[bh] = fmaxf(fmaxf(red[0],red[1]),fmaxf(red[2],red[3]));
  __syncthreads();
  for (int off=32; off; off>>=1) rs = fmaxf(rs, __shfl_down(rs,off,64));
  if ((t&63)==0) red[t>>6]=rs;
  __syncthreads();
  if (t==0) rc[16+bh] = fmaxf(fmaxf(red[0],red[1]),fmaxf(red[2],red[3]));
}
__global__ void k_denom(const float* rc, float* denom){
  float cm=0.f, rm=0.f;
  for (int i=0;i<16;i++){ cm=fmaxf(cm,rc[i]); rm=fmaxf(rm,rc[16+i]); }
  *denom = cm*rm;
}

// ---------- z0 = a2^T / denom ----------
__global__ void k_z0(const float* a2, const float* denom, float* z){
  __shared__ float tile[32][33];
  int bh = blockIdx.z;
  int c0 = blockIdx.x*32, r0 = blockIdx.y*32;
  int x = threadIdx.x & 31, y = threadIdx.x >> 5;
  const float* p = a2 + (long)bh*65536;
  #pragma unroll
  for (int yy=0; yy<32; yy+=8) tile[y+yy][x] = p[(long)(r0+y+yy)*256 + c0 + x];
  __syncthreads();
  float inv = 1.0f / (*denom);
  float* zp = z + (long)bh*65536;
  #pragma unroll
  for (int yy=0; yy<32; yy+=8) zp[(long)(c0+y+yy)*256 + r0 + x] = tile[x][y+yy]*inv;
}

// ---------- batched 256-dim GEMM ----------
__launch_bounds__(256)
__global__ void k_mm256(const float* A, const float* Bm, float* C, float* C2,
                        float d1, float s1, float d2, float s2, int N, int K){
  __shared__ float As[16][68];
  __shared__ float Bs[16][68];
  int bh = blockIdx.z;
  const float* Ap = A  + (long)bh*65536;
  const float* Bp = Bm + (long)bh*K*N;
  int tid = threadIdx.x;
  int m0 = blockIdx.x*64, n0 = blockIdx.y*64;
  int tx = tid & 15, ty = tid >> 4;
  float acc[4][4];
  for (int i=0;i<4;i++) for (int j=0;j<4;j++) acc[i][j]=0.f;
  int mA = tid >> 2, qA = (tid & 3)*4;
  int kB = tid >> 4, nB = (tid & 15)*4;
  for (int k0=0; k0<K; k0+=16){
    float4 a = *(const float4*)(Ap + (long)(m0+mA)*K + k0 + qA);
    As[qA+0][mA]=a.x; As[qA+1][mA]=a.y; As[qA+2][mA]=a.z; As[qA+3][mA]=a.w;
    float4 b = *(const float4*)(Bp + (long)(k0+kB)*N + n0 + nB);
    Bs[kB][nB+0]=b.x; Bs[kB][nB+1]=b.y; Bs[kB][nB+2]=b.z; Bs[kB][nB+3]=b.w;
    __syncthreads();
    #pragma unroll
    for (int kk=0; kk<16; ++kk){
      float4 av = *(const float4*)&As[kk][ty*4];
      float4 bv = *(const float4*)&Bs[kk][tx*4];
      float avv[4]={av.x,av.y,av.z,av.w}, bvv[4]={bv.x,bv.y,bv.z,bv.w};
      #pragma unroll
      for (int i=0;i<4;i++)
        #pragma unroll
        for (int j=0;j<4;j++) acc[i][j] += avv[i]*bvv[j];
    }
    __syncthreads();
  }
  long cb = (long)bh*256*N;
  for (int i=0;i<4;i++){
    int r = m0+ty*4+i;
    for (int j=0;j<4;j++){
      int c = n0+tx*4+j;
      float di = (r==c) ? 1.f : 0.f;
      C[cb + (long)r*N + c] = s1*acc[i][j] + di*d1;
      if (C2) C2[cb + (long)r*N + c] = s2*acc[i][j] + di*d2;
    }
  }
}

// ---------- flash: O = softmax_rows(Q @ K^T) @ V ----------
// OM 0: f32 normalized out; OM 1: bf16 normalized out; OM 2: f32 partial (split-K)
template<int OM>
__launch_bounds__(256)
__global__ void k_flash(const float* Q, const float* Km, const float* Vm, void* Optr,
                        float* ml, int kvlen, long qbs, long kvbs){
  __shared__ float qs[16][68];
  __shared__ float ks[64][68];
  __shared__ float vs[64][68];
  __shared__ float Ss[16][68];
  __shared__ float sc[16], lsh[16];
  int bh = blockIdx.y, qt = blockIdx.x, t = threadIdx.x;
  int sidx = (OM==2) ? blockIdx.z : 0;
  int pbase = sidx * kvlen;
  const float* qp = Q + (long)bh*qbs + (long)qt*16*64;
  { int fidx = t*4; int r = fidx>>6, c = fidx&63;
    float4 a = *(const float4*)(qp + fidx);
    qs[r][c]=a.x; qs[r][c+1]=a.y; qs[r][c+2]=a.z; qs[r][c+3]=a.w; }
  int j = t & 15, pq = t >> 4;
  float m_j = -1e30f, l_j = 0.f;
  float o0=0,o1=0,o2=0,o3=0;
  const float* kp = Km + (long)bh*kvbs;
  const float* vp = Vm + (long)bh*kvbs;
  for (int p0=pbase; p0<pbase+kvlen; p0+=64){
    __syncthreads();
    for (int l=0;l<4;l++){
      int fidx = (l*256 + t)*4; int r = fidx>>6, c = fidx&63;
      float4 a = *(const float4*)(kp + (long)(p0+r)*64 + c);
      ks[r][c]=a.x; ks[r][c+1]=a.y; ks[r][c+2]=a.z; ks[r][c+3]=a.w;
      float4 b = *(const float4*)(vp + (long)(p0+r)*64 + c);
      vs[r][c]=b.x; vs[r][c+1]=b.y; vs[r][c+2]=b.z; vs[r][c+3]=b.w;
    }
    __syncthreads();
    float s0=0,s1=0,s2=0,s3=0;
    #pragma unroll
    for (int d=0;d<64;d++){
      float qv = qs[j][d];
      s0 += qv*ks[pq*4+0][d];
      s1 += qv*ks[pq*4+1][d];
      s2 += qv*ks[pq*4+2][d];
      s3 += qv*ks[pq*4+3][d];
    }
    Ss[j][pq*4+0]=s0; Ss[j][pq*4+1]=s1; Ss[j][pq*4+2]=s2; Ss[j][pq*4+3]=s3;
    __syncthreads();
    if (t < 16){
      float m = m_j;
      #pragma unroll
      for (int p=0;p<64;p++) m = fmaxf(m, Ss[t][p]);
      float scale = __expf(m_j - m);
      float sum = l_j*scale;
      for (int p=0;p<64;p++){ float e = __expf(Ss[t][p]-m); Ss[t][p]=e; sum+=e; }
      m_j = m; l_j = sum; sc[t] = scale;
    }
    __syncthreads();
    float scl = sc[j];
    o0*=scl; o1*=scl; o2*=scl; o3*=scl;
    #pragma unroll
    for (int p=0;p<64;p++){
      float pv = Ss[j][p];
      o0 += pv*vs[p][pq*4+0];
      o1 += pv*vs[p][pq*4+1];
      o2 += pv*vs[p][pq*4+2];
      o3 += pv*vs[p][pq*4+3];
    }
  }
  if constexpr (OM == 2){
    float* op = (float*)Optr + (((long)(sidx*16+bh)*256) + qt*16 + j)*64 + pq*4;
    float4 ov = {o0,o1,o2,o3};
    *(float4*)op = ov;
    if (t<16){
      long mi = (((long)(sidx*16+bh)*256) + qt*16 + t)*2;
      ml[mi] = m_j; ml[mi+1] = l_j;
    }
  } else {
    if (t<16) lsh[t]=l_j;
    __syncthreads();
    float invl = 1.f/lsh[j];
    if constexpr (OM == 1){
      u16* op = (u16*)Optr + (long)bh*qbs + ((long)qt*16 + j)*64 + pq*4;
      op[0]=f2bf(o0*invl); op[1]=f2bf(o1*invl); op[2]=f2bf(o2*invl); op[3]=f2bf(o3*invl);
    } else {
      float* op = (float*)Optr + (long)bh*qbs + ((long)qt*16 + j)*64 + pq*4;
      float4 ov = {o0*invl, o1*invl, o2*invl, o3*invl};
      *(float4*)op = ov;
    }
  }
}

// ---------- combine split-K flash partials ----------
__global__ void k_fcomb(const float* op, const float* ml, float* w3){
  int bh = blockIdx.y, rt = blockIdx.x, t = threadIdx.x;
  int row = rt*16 + (t>>4), d0 = (t&15)*4;
  float M = -1e30f;
  for (int s=0;s<8;s++) M = fmaxf(M, ml[(((long)(s*16+bh)*256)+row)*2]);
  float lt = 0.f;
  float4 o = {0,0,0,0};
  for (int s=0;s<8;s++){
    long base = ((long)(s*16+bh)*256)+row;
    float w = __expf(ml[base*2]-M);
    lt += ml[base*2+1]*w;
    float4 ov = *(const float4*)&op[base*64 + d0];
    o.x += ov.x*w; o.y += ov.y*w; o.z += ov.z*w; o.w += ov.w*w;
  }
  float inv = 1.f/lt;
  float4 r = {o.x*inv, o.y*inv, o.z*inv, o.w*inv};
  *(float4*)&w3[((long)bh*256+row)*64 + d0] = r;
}

// ---------- depthwise conv residual, heads(bf16) += res ----------
__launch_bounds__(256)
__global__ void k_conv(const float* v, const float* cw, u16* heads){
  __shared__ float vsl[160][64];
  __shared__ float cws[33];
  int bh = blockIdx.y, pt = blockIdx.x, t = threadIdx.x;
  int hh = bh & 7;
  if (t < 33) cws[t] = cw[hh*33 + t];
  int p0 = pt*128;
  const float* vp = v + (long)bh*8192*64;
  for (int l=0;l<10;l++){
    int fidx = (l*256 + t)*4;
    int r = fidx>>6, c = fidx&63;
    int gp = p0 - 16 + r;
    if (gp>=0 && gp<8192){
      float4 a = *(const float4*)(vp + (long)gp*64 + c);
      vsl[r][c]=a.x; vsl[r][c+1]=a.y; vsl[r][c+2]=a.z; vsl[r][c+3]=a.w;
    } else {
      vsl[r][c]=0.f; vsl[r][c+1]=0.f; vsl[r][c+2]=0.f; vsl[r][c+3]=0.f;
    }
  }
  __syncthreads();
  int d = t & 63, pg = t >> 6;
  u16* hp = heads + ((long)bh*8192 + p0)*64;
  for (int pp=0; pp<32; pp++){
    int pl = pp*4 + pg;
    float acc = 0.f;
    #pragma unroll
    for (int tt=0; tt<33; tt++) acc += vsl[pl+tt][d]*cws[tt];
    long idx = (long)pl*64 + d;
    hp[idx] = f2bf(bf2f(hp[idx]) + acc);
  }
}

// ---------- final: LN(cls) @ fc2 + softmax + argmax ----------
__global__ void k_final(const float* hbuf, const float* g, const float* bt,
                        const float* fw, const float* fb, float* outp){
  int b = blockIdx.x, t = threadIdx.x;
  __shared__ float red[4];
  __shared__ float sx[512];
  __shared__ float lg[4];
  const float* x = hbuf + ((long)b*8192+191)*512;
  float2 xv = *(const float2*)(x + t*2);
  float s = xv.x + xv.y;
  for (int off=32; off; off>>=1) s += __shfl_down(s,off,64);
  if ((t&63)==0) red[t>>6]=s;
  __syncthreads();
  float mean = (red[0]+red[1]+red[2]+red[3])*(1.f/512.f);
  __syncthreads();
  float d0 = xv.x-mean, d1 = xv.y-mean;
  float ssq = d0*d0 + d1*d1;
  for (int off=32; off; off>>=1) ssq += __shfl_down(ssq,off,64);
  if ((t&63)==0) red[t>>6]=ssq;
  __syncthreads();
  float rstd = rsqrtf((red[0]+red[1]+red[2]+red[3])*(1.f/512.f) + 1e-5f);
  sx[t*2]   = d0*rstd*g[t*2]   + bt[t*2];
  sx[t*2+1] = d1*rstd*g[t*2+1] + bt[t*2+1];
  __syncthreads();
  int c = t>>7, jj = t&127;
  float part = 0.f;
  for (int kk=jj; kk<512; kk+=128) part += sx[kk]*fw[(long)kk*2 + c];
  for (int off=1; off<64; off<<=1) part += __shfl_xor(part,off,64);
  if ((t&63)==0) lg[t>>6]=part;
  __syncthreads();
  if (t==0){
    float l0 = lg[0]+lg[1] + fb[0];
    float l1 = lg[2]+lg[3] + fb[1];
    float m = fmaxf(l0,l1);
    float e0 = __expf(l0-m), e1 = __expf(l1-m);
    float inv = 1.f/(e0+e1);
    outp[b*2+0]=l0; outp[b*2+1]=l1;
    outp[4+b*2+0]=e0*inv; outp[4+b*2+1]=e1*inv;
    outp[8+b]=(l1>l0) ? 1.f : 0.f;
  }
}

// ===================== host launch =====================
extern "C" void kernel_launch(void* const* d_in, const int* in_sizes, int n_in,
                              void* d_out, int out_size, void* d_ws, size_t ws_size,
                              hipStream_t stream){
  (void)in_sizes; (void)n_in; (void)out_size; (void)ws_size;
  const long TOK = (long)2*8192*512;
  float* W    = (float*)d_ws;
  float* rc   = W;                         // 64 floats
  float* h    = W + 64;
  float* q    = h + TOK;
  float* k    = q + TOK;
  float* v    = k + TOK;
  u16*  xlnb  = (u16*)(v + TOK);           // 16384*512 u16
  u16*  headsb= xlnb + (long)16384*512;    // 16384*512 u16
  u16*  wT    = headsb + (long)16384*512;  // 1,048,576 u16
  float* ql   = (float*)(wT + 1048576);
  float* kl   = ql + 262144;
  float* w3   = kl + 262144;
  float* zw   = w3 + 262144;
  float* a2   = zw + 262144;
  float* z    = a2 + 1048576;
  float* z2   = z  + 1048576;
  float* xz   = z2 + 1048576;
  float* t1   = xz + 1048576;
  float* t2   = t1 + 1048576;
  float* op   = xz;                        // flash partials alias xz+t1 (2,097,152 f)
  float* ml   = t2;                        // 65,536 f

  dim3 B(256);

  k_cls<<<dim3(2), B, 0, stream>>>((const float*)d_in[3], h);
  // fc1: wT = fc1_w^T bf16 [512][1024]
  k_cvtT<<<dim3(16,32), B, 0, stream>>>((const float*)d_in[1], wT, 1024, 512);
  k_gemm<0><<<dim3(125,4), B, 0, stream>>>(d_in[0], wT, (const float*)d_in[2],
                                           h, nullptr,nullptr,nullptr, 16000,512,1024);

  for (int blk=0; blk<2; ++blk){
    const float* lng  = (const float*)d_in[blk?10:4];
    const float* lnb  = (const float*)d_in[blk?11:5];
    const float* qkvw = (const float*)d_in[blk?12:6];
    const float* outw = (const float*)d_in[blk?13:7];
    const float* outb = (const float*)d_in[blk?14:8];
    const float* cw   = (const float*)d_in[blk?15:9];

    k_ln<<<dim3(16384), B, 0, stream>>>(h, lng, lnb, xlnb);

    k_cvtT<<<dim3(48,16), B, 0, stream>>>(qkvw, wT, 512, 1536);
    k_gemm<1><<<dim3(128,12), B, 0, stream>>>(xlnb, wT, nullptr,
                                              nullptr, q,k,v, 16384,1536,512);

    k_landmark<<<dim3(256,16), dim3(64), 0, stream>>>(q, ql);
    k_landmark<<<dim3(256,16), dim3(64), 0, stream>>>(k, kl);

    k_a2<<<dim3(16,16), B, 0, stream>>>(ql, kl, a2);
    k_colrow<<<dim3(16), B, 0, stream>>>(a2, rc);
    k_denom<<<dim3(1), dim3(1), 0, stream>>>(rc, rc+32);
    k_z0<<<dim3(8,8,16), B, 0, stream>>>(a2, rc+32, z);

    for (int it=0; it<6; ++it){
      float* zin  = (it&1) ? z2 : z;
      float* zout = (it&1) ? z  : z2;
      k_mm256<<<dim3(4,4,16), B, 0, stream>>>(a2, zin, xz, t1, 0.f,1.f,  7.f,-1.f, 256,256);
      k_mm256<<<dim3(4,4,16), B, 0, stream>>>(xz, t1, t2, nullptr, 15.f,-1.f, 0.f,0.f, 256,256);
      k_mm256<<<dim3(4,4,16), B, 0, stream>>>(xz, t2, t1, nullptr, 13.f,-1.f, 0.f,0.f, 256,256);
      k_mm256<<<dim3(4,4,16), B, 0, stream>>>(zin, t1, zout, nullptr, 0.f,0.25f, 0.f,0.f, 256,256);
    }

    // w3 = softmax(q_l @ k^T) @ v  via split-K flash (8 chunks of 1024)
    k_flash<2><<<dim3(16,16,8), B, 0, stream>>>(ql, k, v, op, ml, 1024, 16384L, 524288L);
    k_fcomb<<<dim3(16,16), B, 0, stream>>>(op, ml, w3);
    // zw = z @ w3
    k_mm256<<<dim3(4,1,16), B, 0, stream>>>(z, w3, zw, nullptr, 0.f,1.f, 0.f,0.f, 64,256);
    // heads(bf16) = softmax(q @ k_l^T) @ zw
    k_flash<1><<<dim3(512,16), B, 0, stream>>>(q, kl, zw, headsb, nullptr, 256, 524288L, 16384L);

    k_conv<<<dim3(64,16), B, 0, stream>>>(v, cw, headsb);

    k_cvtT<<<dim3(16,16), B, 0, stream>>>(outw, wT, 512, 512);
    k_gemm<2><<<dim3(128,4), B, 0, stream>>>(headsb, wT, outb,
                                             h, nullptr,nullptr,nullptr, 16384,512,512);
  }

  k_final<<<dim3(2), B, 0, stream>>>(h, (const float*)d_in[16], (const float*)d_in[17],
                                     (const float*)d_in[18], (const float*)d_in[19], (float*)d_out);
}

// Round 3
// 1600.565 us; speedup vs baseline: 2.4553x; 1.7437x over previous
//
#include <hip/hip_runtime.h>

typedef unsigned short u16;
typedef __attribute__((ext_vector_type(8))) short short8;
typedef __attribute__((ext_vector_type(4))) float f32x4;

__device__ __forceinline__ float bf2f(u16 x){
  union { unsigned u; float f; } c; c.u = ((unsigned)x) << 16; return c.f;
}
__device__ __forceinline__ u16 f2bf(float f){
  union { float f; unsigned u; } c; c.f = f;
  unsigned u = c.u;
  return (u16)((u + 0x7FFFu + ((u >> 16) & 1u)) >> 16);
}
__device__ __forceinline__ unsigned pk2(float a, float b){
  return (unsigned)f2bf(a) | ((unsigned)f2bf(b) << 16);
}

__device__ __forceinline__ void gload16(const void* g, void* l){
  __builtin_amdgcn_global_load_lds(
    (const __attribute__((address_space(1))) void*)g,
    (__attribute__((address_space(3))) void*)l, 16, 0, 0);
}

// ---------- cls token ----------
__global__ void k_cls(const float* cls, float* h){
  int b = blockIdx.x, t = threadIdx.x;
  for (int c=t; c<512; c+=256)
    h[((long)b*8192+191)*512 + c] = cls[c];
}

// ---------- weight convert + transpose: W f32 [K][N] -> wT bf16 [N][K] ----------
__global__ void k_cvtT(const float* Wm, u16* wT, int K, int N){
  __shared__ float tile[32][33];
  int n0 = blockIdx.x*32, k0 = blockIdx.y*32;
  int x = threadIdx.x & 31, y = threadIdx.x >> 5;
  #pragma unroll
  for (int p=0;p<4;p++) tile[y+8*p][x] = Wm[(long)(k0+y+8*p)*N + n0 + x];
  __syncthreads();
  #pragma unroll
  for (int p=0;p<4;p++) wT[(long)(n0+y+8*p)*K + k0 + x] = f2bf(tile[x][y+8*p]);
}

// ---------- MFMA GEMM: 128x128 tile, BK=32, 4 waves ----------
template<int MODE>
__launch_bounds__(256)
__global__ void k_gemm(const void* Av, const u16* Bt, const float* bias,
                       float* hout, float* qo, float* ko, float* vo,
                       int M, int N, int K){
  __shared__ __align__(16) u16 As[128*32];
  __shared__ __align__(16) u16 Bs[128*32];
  const int tid = threadIdx.x;
  const int wave = tid>>6, lane = tid&63;
  const int m0 = blockIdx.x*128, n0 = blockIdx.y*128;
  const int wr = wave>>1, wc = wave&1;
  f32x4 acc[4][4];
  #pragma unroll
  for (int i=0;i<4;i++)
    #pragma unroll
    for (int j=0;j<4;j++) acc[i][j] = (f32x4){0.f,0.f,0.f,0.f};

  for (int k0=0; k0<K; k0+=32){
    if constexpr (MODE == 0){
      int r = tid>>1, half = tid&1;
      const float* gp = (const float*)Av + (long)(m0+r)*K + k0 + half*16;
      float4 f0 = *(const float4*)(gp+0);
      float4 f1 = *(const float4*)(gp+4);
      float4 f2 = *(const float4*)(gp+8);
      float4 f3 = *(const float4*)(gp+12);
      uint4 pa, pb;
      pa.x = pk2(f0.x,f0.y); pa.y = pk2(f0.z,f0.w);
      pa.z = pk2(f1.x,f1.y); pa.w = pk2(f1.z,f1.w);
      pb.x = pk2(f2.x,f2.y); pb.y = pk2(f2.z,f2.w);
      pb.z = pk2(f3.x,f3.y); pb.w = pk2(f3.z,f3.w);
      uint4* dst = (uint4*)&As[r*32 + half*16];
      dst[0] = pa; dst[1] = pb;
    } else {
      #pragma unroll
      for (int ci=0; ci<2; ++ci){
        int c = wave*2 + ci;
        int r = (c<<4) + (lane>>2), kq = lane&3;
        const u16* gp;
        if constexpr (MODE == 1){
          gp = (const u16*)Av + (long)(m0+r)*K + k0 + kq*8;
        } else {
          int rr = m0 + r; int b = rr>>13, pos = rr&8191;
          int cc = k0 + kq*8; int hh = cc>>6, d = cc&63;
          gp = (const u16*)Av + ((long)(b*8+hh)*8192 + pos)*64 + d;
        }
        gload16(gp, &As[c*512]);
      }
    }
    #pragma unroll
    for (int ci=0; ci<2; ++ci){
      int c = wave*2 + ci;
      int r = (c<<4) + (lane>>2), kq = lane&3;
      gload16(Bt + (long)(n0+r)*K + k0 + kq*8, &Bs[c*512]);
    }
    __syncthreads();
    short8 af[4], bf[4];
    int arow = wr*64 + (lane&15);
    int brow = wc*64 + (lane&15);
    int koff = (lane>>4)*8;
    #pragma unroll
    for (int i=0;i<4;i++){
      af[i] = *(const short8*)&As[(arow + i*16)*32 + koff];
      bf[i] = *(const short8*)&Bs[(brow + i*16)*32 + koff];
    }
    #pragma unroll
    for (int i=0;i<4;i++)
      #pragma unroll
      for (int j=0;j<4;j++)
        acc[i][j] = __builtin_amdgcn_mfma_f32_16x16x32_bf16(af[i], bf[j], acc[i][j], 0,0,0);
    __syncthreads();
  }

  const int lr = lane>>4, lc = lane&15;
  if constexpr (MODE == 0){
    #pragma unroll
    for (int j=0;j<4;j++){
      int cb = n0 + wc*64 + j*16 + lc;
      float bb = bias[cb];
      #pragma unroll
      for (int i=0;i<4;i++){
        #pragma unroll
        for (int r=0;r<4;r++){
          int row = m0 + wr*64 + i*16 + lr*4 + r;
          int b = (row >= 8000) ? 1 : 0;
          int tok = row - b*8000;
          hout[((long)(b*8192 + 192 + tok))*512 + cb] = fmaxf(acc[i][j][r] + bb, 0.f);
        }
      }
    }
  } else if constexpr (MODE == 1){
    #pragma unroll
    for (int j=0;j<4;j++){
      int cb = n0 + wc*64 + j*16 + lc;
      int which = cb>>9, head = (cb>>6)&7, d = cb&63;
      float* base = (which==0) ? qo : (which==1 ? ko : vo);
      float scale = (which==0) ? 0.125f : 1.0f;
      #pragma unroll
      for (int i=0;i<4;i++){
        #pragma unroll
        for (int r=0;r<4;r++){
          int row = m0 + wr*64 + i*16 + lr*4 + r;
          int b = row>>13, pos = row&8191;
          base[((long)(b*8+head)*8192 + pos)*64 + d] = acc[i][j][r]*scale;
        }
      }
    }
  } else {
    #pragma unroll
    for (int j=0;j<4;j++){
      int cb = n0 + wc*64 + j*16 + lc;
      float bb = bias[cb];
      #pragma unroll
      for (int i=0;i<4;i++){
        #pragma unroll
        for (int r=0;r<4;r++){
          int row = m0 + wr*64 + i*16 + lr*4 + r;
          int pos = row&8191;
          if (pos >= 191) hout[(long)row*512 + cb] += acc[i][j][r] + bb;
        }
      }
    }
  }
}

// ---------- layernorm: h f32 -> xln bf16 (pad rows -> 0) ----------
__global__ void k_ln(const float* hsrc, const float* g, const float* bt, u16* xlnb){
  int row = blockIdx.x;
  int pos = row & 8191;
  int t = threadIdx.x;
  long base = (long)row*512 + t*2;
  if (pos < 191){ *(unsigned*)&xlnb[base] = 0u; return; }
  float2 x = *(const float2*)(hsrc + base);
  __shared__ float red[4];
  float s = x.x + x.y;
  for (int off=32; off; off>>=1) s += __shfl_down(s, off, 64);
  if ((t&63)==0) red[t>>6]=s;
  __syncthreads();
  float mean = (red[0]+red[1]+red[2]+red[3]) * (1.f/512.f);
  __syncthreads();
  float d0 = x.x-mean, d1 = x.y-mean;
  float ss = d0*d0 + d1*d1;
  for (int off=32; off; off>>=1) ss += __shfl_down(ss, off, 64);
  if ((t&63)==0) red[t>>6]=ss;
  __syncthreads();
  float rstd = rsqrtf((red[0]+red[1]+red[2]+red[3])*(1.f/512.f) + 1e-5f);
  float o0 = d0*rstd*g[t*2]   + bt[t*2];
  float o1 = d1*rstd*g[t*2+1] + bt[t*2+1];
  *(unsigned*)&xlnb[base] = pk2(o0, o1);
}

// ---------- landmark means ----------
__global__ void k_landmark(const float* src, float* dst){
  int g = blockIdx.x, bh = blockIdx.y, d = threadIdx.x;
  const float* p = src + (((long)bh*8192) + g*32)*64 + d;
  float s = 0.f;
  #pragma unroll
  for (int j=0;j<32;j++) s += p[j*64];
  dst[((long)bh*256 + g)*64 + d] = s*(1.f/32.f);
}

// ---------- a2 = softmax(q_l @ k_l^T) ----------
__launch_bounds__(256)
__global__ void k_a2(const float* qlm, const float* klm, float* a2){
  __shared__ float qls[16][68];
  __shared__ float kls[64][65];
  __shared__ float Sf[16][260];
  __shared__ float red[4];
  int bh = blockIdx.y, rt = blockIdx.x, t = threadIdx.x;
  const float* qp = qlm + ((long)bh*256 + rt*16)*64;
  { int fidx = t*4; int r = fidx>>6, c = fidx&63;
    float4 a = *(const float4*)(qp + fidx);
    qls[r][c]=a.x; qls[r][c+1]=a.y; qls[r][c+2]=a.z; qls[r][c+3]=a.w; }
  const float* kp = klm + (long)bh*16384;
  int cl = t & 63, ig = t >> 6;
  for (int kt=0; kt<4; ++kt){
    __syncthreads();
    for (int l=0;l<4;l++){
      int fidx = (l*256+t)*4; int r = fidx>>6, c = fidx&63;
      float4 a = *(const float4*)(kp + (long)(kt*64+r)*64 + c);
      kls[r][c]=a.x; kls[r][c+1]=a.y; kls[r][c+2]=a.z; kls[r][c+3]=a.w;
    }
    __syncthreads();
    float s0=0,s1=0,s2=0,s3=0;
    #pragma unroll
    for (int d=0;d<64;d++){
      float kv = kls[cl][d];
      s0 += qls[ig*4+0][d]*kv;
      s1 += qls[ig*4+1][d]*kv;
      s2 += qls[ig*4+2][d]*kv;
      s3 += qls[ig*4+3][d]*kv;
    }
    Sf[ig*4+0][kt*64+cl]=s0;
    Sf[ig*4+1][kt*64+cl]=s1;
    Sf[ig*4+2][kt*64+cl]=s2;
    Sf[ig*4+3][kt*64+cl]=s3;
  }
  __syncthreads();
  float* arow = a2 + ((long)bh*256 + rt*16)*256;
  for (int i=0;i<16;i++){
    float val = Sf[i][t];
    float m = val;
    for (int off=1; off<64; off<<=1) m = fmaxf(m, __shfl_xor(m,off,64));
    if ((t&63)==0) red[t>>6]=m;
    __syncthreads();
    m = fmaxf(fmaxf(red[0],red[1]),fmaxf(red[2],red[3]));
    __syncthreads();
    float e = __expf(val - m);
    float sum = e;
    for (int off=1; off<64; off<<=1) sum += __shfl_xor(sum,off,64);
    if ((t&63)==0) red[t>>6]=sum;
    __syncthreads();
    sum = red[0]+red[1]+red[2]+red[3];
    __syncthreads();
    arow[(long)i*256 + t] = e/sum;
  }
}

// ---------- pinv denominator ----------
__global__ void k_colrow(const float* a2, float* rc){
  int bh = blockIdx.x, t = threadIdx.x;
  const float* p = a2 + (long)bh*65536;
  float cs=0.f, rs=0.f;
  for (int r=0;r<256;r++) cs += fabsf(p[(long)r*256 + t]);
  for (int c=0;c<256;c++) rs += fabsf(p[(long)t*256 + c]);
  __shared__ float red[4];
  for (int off=32; off; off>>=1) cs = fmaxf(cs, __shfl_down(cs,off,64));
  if ((t&63)==0) red[t>>6]=cs;
  __syncthreads();
  if (t==0) rc[bh] = fmaxf(fmaxf(red[0],red[1]),fmaxf(red[2],red[3]));
  __syncthreads();
  for (int off=32; off; off>>=1) rs = fmaxf(rs, __shfl_down(rs,off,64));
  if ((t&63)==0) red[t>>6]=rs;
  __syncthreads();
  if (t==0) rc[16+bh] = fmaxf(fmaxf(red[0],red[1]),fmaxf(red[2],red[3]));
}
__global__ void k_denom(const float* rc, float* denom){
  float cm=0.f, rm=0.f;
  for (int i=0;i<16;i++){ cm=fmaxf(cm,rc[i]); rm=fmaxf(rm,rc[16+i]); }
  *denom = cm*rm;
}

// ---------- z0 = a2^T / denom ----------
__global__ void k_z0(const float* a2, const float* denom, float* z){
  __shared__ float tile[32][33];
  int bh = blockIdx.z;
  int c0 = blockIdx.x*32, r0 = blockIdx.y*32;
  int x = threadIdx.x & 31, y = threadIdx.x >> 5;
  const float* p = a2 + (long)bh*65536;
  #pragma unroll
  for (int yy=0; yy<32; yy+=8) tile[y+yy][x] = p[(long)(r0+y+yy)*256 + c0 + x];
  __syncthreads();
  float inv = 1.0f / (*denom);
  float* zp = z + (long)bh*65536;
  #pragma unroll
  for (int yy=0; yy<32; yy+=8) zp[(long)(c0+y+yy)*256 + r0 + x] = tile[x][y+yy]*inv;
}

// ---------- batched 256-dim GEMM (f32), optional bf16-transposed out ----------
__launch_bounds__(256)
__global__ void k_mm256(const float* A, const float* Bm, float* C, float* C2, u16* CT,
                        float d1, float s1, float d2, float s2, int N, int K){
  __shared__ float As[16][68];
  __shared__ float Bs[16][68];
  int bh = blockIdx.z;
  const float* Ap = A  + (long)bh*65536;
  const float* Bp = Bm + (long)bh*K*N;
  int tid = threadIdx.x;
  int m0 = blockIdx.x*64, n0 = blockIdx.y*64;
  int tx = tid & 15, ty = tid >> 4;
  float acc[4][4];
  for (int i=0;i<4;i++) for (int j=0;j<4;j++) acc[i][j]=0.f;
  int mA = tid >> 2, qA = (tid & 3)*4;
  int kB = tid >> 4, nB = (tid & 15)*4;
  for (int k0=0; k0<K; k0+=16){
    float4 a = *(const float4*)(Ap + (long)(m0+mA)*K + k0 + qA);
    As[qA+0][mA]=a.x; As[qA+1][mA]=a.y; As[qA+2][mA]=a.z; As[qA+3][mA]=a.w;
    float4 b = *(const float4*)(Bp + (long)(k0+kB)*N + n0 + nB);
    Bs[kB][nB+0]=b.x; Bs[kB][nB+1]=b.y; Bs[kB][nB+2]=b.z; Bs[kB][nB+3]=b.w;
    __syncthreads();
    #pragma unroll
    for (int kk=0; kk<16; ++kk){
      float4 av = *(const float4*)&As[kk][ty*4];
      float4 bv = *(const float4*)&Bs[kk][tx*4];
      float avv[4]={av.x,av.y,av.z,av.w}, bvv[4]={bv.x,bv.y,bv.z,bv.w};
      #pragma unroll
      for (int i=0;i<4;i++)
        #pragma unroll
        for (int j=0;j<4;j++) acc[i][j] += avv[i]*bvv[j];
    }
    __syncthreads();
  }
  long cb = (long)bh*256*N;
  for (int i=0;i<4;i++){
    int r = m0+ty*4+i;
    for (int j=0;j<4;j++){
      int c = n0+tx*4+j;
      float di = (r==c) ? 1.f : 0.f;
      float val = s1*acc[i][j] + di*d1;
      if (C)  C[cb + (long)r*N + c] = val;
      if (C2) C2[cb + (long)r*N + c] = s2*acc[i][j] + di*d2;
      if (CT) CT[((long)bh*N + c)*256 + r] = f2bf(val);
    }
  }
}

// ---------- v -> vt bf16 transpose: vt[bh][64][8192] ----------
__launch_bounds__(256)
__global__ void k_vt(const float* v, u16* vt){
  __shared__ float tile[32][68];
  int pt = blockIdx.x, bh = blockIdx.y, t = threadIdx.x;
  int p = t>>3, d0 = (t&7)*8;
  const float* src = v + ((long)bh*8192 + pt*32 + p)*64 + d0;
  float4 a = *(const float4*)src;
  float4 b = *(const float4*)(src+4);
  tile[p][d0+0]=a.x; tile[p][d0+1]=a.y; tile[p][d0+2]=a.z; tile[p][d0+3]=a.w;
  tile[p][d0+4]=b.x; tile[p][d0+5]=b.y; tile[p][d0+6]=b.z; tile[p][d0+7]=b.w;
  __syncthreads();
  int pos2 = (t&15)*2;
  #pragma unroll
  for (int ll=0; ll<4; ++ll){
    int d = (t>>4) + 16*ll;
    unsigned val = pk2(tile[pos2][d], tile[pos2+1][d]);
    *(unsigned*)&vt[((long)(bh*64 + d))*8192 + pt*32 + pos2] = val;
  }
}

// ---------- MFMA flash: O = softmax_rows(Q @ K^T) @ V ----------
// 4 waves x 16 q-rows; KV tiles of 64. Q,K f32 in global; V pre-transposed bf16.
// OM 0: split-K partials op/ml.  OM 1: normalized, bf16 += into hb.
template<int OM>
__launch_bounds__(256)
__global__ void k_flash2(const float* Q, const float* K, const u16* VT,
                         float* op, float* ml, u16* hb,
                         int kvchunk, long qbh, long kbh, long vtbh, int vtrow){
  __shared__ __align__(16) u16 KT[64*64];
  __shared__ __align__(16) u16 VTs[64*64];
  __shared__ __align__(16) u16 Pb[4*16*72];
  int bh = blockIdx.y, qt = blockIdx.x, sk = (OM==0) ? blockIdx.z : 0;
  int t = threadIdx.x, w = t>>6, l = t&63;
  int lq = l&15, hi = l>>4;

  // Q fragments straight from global f32 (per-lane), cvt to bf16
  short8 qf[2];
  {
    const float* qp = Q + (long)bh*qbh + (long)(qt*64 + w*16 + lq)*64 + hi*8;
    #pragma unroll
    for (int kh=0; kh<2; ++kh){
      float4 f0 = *(const float4*)(qp + kh*32);
      float4 f1 = *(const float4*)(qp + kh*32 + 4);
      union { short8 s; uint4 u; } c;
      c.u.x = pk2(f0.x,f0.y); c.u.y = pk2(f0.z,f0.w);
      c.u.z = pk2(f1.x,f1.y); c.u.w = pk2(f1.z,f1.w);
      qf[kh] = c.s;
    }
  }
  float m_run = -1e30f, l_run = 0.f;
  f32x4 o[4];
  #pragma unroll
  for (int i=0;i<4;i++) o[i] = (f32x4){0.f,0.f,0.f,0.f};

  const float* kbase = K + (long)bh*kbh;
  const u16* vtbase = VT + (long)bh*vtbh;
  char* Pw = (char*)&Pb[w*16*72];
  int kv0 = sk*kvchunk;

  for (int p0 = kv0; p0 < kv0 + kvchunk; p0 += 64){
    // stage K tile (reg, f32->bf16, XOR-swizzled)
    {
      int r = w*16 + (l>>2), d0 = (l&3)*16;
      const float* kr = kbase + (long)(p0 + r)*64 + d0;
      float4 f0 = *(const float4*)(kr+0);
      float4 f1 = *(const float4*)(kr+4);
      float4 f2 = *(const float4*)(kr+8);
      float4 f3 = *(const float4*)(kr+12);
      float fv[16] = {f0.x,f0.y,f0.z,f0.w,f1.x,f1.y,f1.z,f1.w,
                      f2.x,f2.y,f2.z,f2.w,f3.x,f3.y,f3.z,f3.w};
      #pragma unroll
      for (int m=0;m<8;m++){
        int d = d0 + 2*m;
        int byte = (r*128 + d*2) ^ ((r&7)<<4);
        *(unsigned*)((char*)KT + byte) = pk2(fv[2*m], fv[2*m+1]);
      }
    }
    // stage V^T tile via global_load_lds, pre-swizzled source
    #pragma unroll
    for (int ii=0; ii<2; ++ii){
      int inst = w*2 + ii;
      int d = inst*8 + (l>>3);
      int srcoff = ((l&7)*16) ^ ((d&7)<<4);
      const char* src = (const char*)(vtbase + (long)d*vtrow + p0) + srcoff;
      gload16(src, (char*)VTs + inst*1024);
    }
    __syncthreads();
    // S^T = K @ Q^T  (rows=kv, cols=q)
    f32x4 s[4];
    #pragma unroll
    for (int i=0;i<4;i++){
      s[i] = (f32x4){0.f,0.f,0.f,0.f};
      #pragma unroll
      for (int kh=0;kh<2;kh++){
        int kvr = i*16 + lq;
        int byte = (kvr*128 + hi*16 + kh*64) ^ ((kvr&7)<<4);
        short8 kf = *(const short8*)((const char*)KT + byte);
        s[i] = __builtin_amdgcn_mfma_f32_16x16x32_bf16(kf, qf[kh], s[i], 0,0,0);
      }
    }
    // wave-parallel online softmax (per q=lane&15)
    float tm = -1e30f;
    #pragma unroll
    for (int i=0;i<4;i++)
      #pragma unroll
      for (int r=0;r<4;r++) tm = fmaxf(tm, s[i][r]);
    tm = fmaxf(tm, __shfl_xor(tm, 16));
    tm = fmaxf(tm, __shfl_xor(tm, 32));
    float mnew = fmaxf(m_run, tm);
    float scale = __expf(m_run - mnew);
    float tsum = 0.f;
    #pragma unroll
    for (int i=0;i<4;i++)
      #pragma unroll
      for (int r=0;r<4;r++){ float e = __expf(s[i][r]-mnew); s[i][r]=e; tsum += e; }
    tsum += __shfl_xor(tsum, 16);
    tsum += __shfl_xor(tsum, 32);
    l_run = l_run*scale + tsum;
    m_run = mnew;
    #pragma unroll
    for (int i=0;i<4;i++)
      #pragma unroll
      for (int r=0;r<4;r++) o[i][r] *= scale;
    // P -> wave-private LDS (bf16, [16 q][72 kv])
    #pragma unroll
    for (int i=0;i<4;i++){
      int byte = lq*144 + (i*16 + hi*4)*2;
      *(unsigned*)(Pw + byte)     = pk2(s[i][0], s[i][1]);
      *(unsigned*)(Pw + byte + 4) = pk2(s[i][2], s[i][3]);
    }
    // PV: O^T += V^T @ P^T (rows=d, cols=q)
    short8 pf[2];
    #pragma unroll
    for (int kh=0;kh<2;kh++)
      pf[kh] = *(const short8*)(Pw + lq*144 + hi*16 + kh*64);
    #pragma unroll
    for (int i=0;i<4;i++){
      #pragma unroll
      for (int kh=0;kh<2;kh++){
        int d = i*16 + lq;
        int byte = (d*128 + hi*16 + kh*64) ^ ((d&7)<<4);
        short8 vf = *(const short8*)((const char*)VTs + byte);
        o[i] = __builtin_amdgcn_mfma_f32_16x16x32_bf16(vf, pf[kh], o[i], 0,0,0);
      }
    }
    __syncthreads();
  }

  int qrow = qt*64 + w*16 + lq;
  if constexpr (OM == 0){
    long ob = ((long)(sk*16+bh)*256 + qrow)*64;
    #pragma unroll
    for (int i=0;i<4;i++)
      #pragma unroll
      for (int r=0;r<4;r++) op[ob + i*16 + hi*4 + r] = o[i][r];
    if (l < 16){
      long mi = ((long)(sk*16+bh)*256 + qt*64 + w*16 + l)*2;
      ml[mi] = m_run; ml[mi+1] = l_run;
    }
  } else {
    float invl = 1.f/l_run;
    long hb0 = ((long)bh*8192 + qrow)*64;
    #pragma unroll
    for (int i=0;i<4;i++)
      #pragma unroll
      for (int r=0;r<4;r++){
        long idx = hb0 + i*16 + hi*4 + r;
        hb[idx] = f2bf(bf2f(hb[idx]) + o[i][r]*invl);
      }
  }
}

// ---------- combine split-K flash partials (16 chunks) ----------
__global__ void k_fcomb(const float* op, const float* ml, float* w3){
  int bh = blockIdx.y, rt = blockIdx.x, t = threadIdx.x;
  int row = rt*16 + (t>>4), d0 = (t&15)*4;
  float M = -1e30f;
  for (int s=0;s<16;s++) M = fmaxf(M, ml[(((long)(s*16+bh)*256)+row)*2]);
  float lt = 0.f;
  float4 o = {0,0,0,0};
  for (int s=0;s<16;s++){
    long base = ((long)(s*16+bh)*256)+row;
    float w = __expf(ml[base*2]-M);
    lt += ml[base*2+1]*w;
    float4 ov = *(const float4*)&op[base*64 + d0];
    o.x += ov.x*w; o.y += ov.y*w; o.z += ov.z*w; o.w += ov.w*w;
  }
  float inv = 1.f/lt;
  float4 r = {o.x*inv, o.y*inv, o.z*inv, o.w*inv};
  *(float4*)&w3[((long)bh*256+row)*64 + d0] = r;
}

// ---------- depthwise conv residual -> headsb (init write) ----------
__launch_bounds__(256)
__global__ void k_conv(const float* v, const float* cw, u16* heads){
  __shared__ float vsl[160][64];
  __shared__ float cws[33];
  int bh = blockIdx.y, pt = blockIdx.x, t = threadIdx.x;
  int hh = bh & 7;
  if (t < 33) cws[t] = cw[hh*33 + t];
  int p0 = pt*128;
  const float* vp = v + (long)bh*8192*64;
  for (int l=0;l<10;l++){
    int fidx = (l*256 + t)*4;
    int r = fidx>>6, c = fidx&63;
    int gp = p0 - 16 + r;
    if (gp>=0 && gp<8192){
      float4 a = *(const float4*)(vp + (long)gp*64 + c);
      vsl[r][c]=a.x; vsl[r][c+1]=a.y; vsl[r][c+2]=a.z; vsl[r][c+3]=a.w;
    } else {
      vsl[r][c]=0.f; vsl[r][c+1]=0.f; vsl[r][c+2]=0.f; vsl[r][c+3]=0.f;
    }
  }
  __syncthreads();
  int d = t & 63, pg = t >> 6;
  u16* hp = heads + ((long)bh*8192 + p0)*64;
  for (int pp=0; pp<32; pp++){
    int pl = pp*4 + pg;
    float acc = 0.f;
    #pragma unroll
    for (int tt=0; tt<33; tt++) acc += vsl[pl+tt][d]*cws[tt];
    hp[(long)pl*64 + d] = f2bf(acc);
  }
}

// ---------- final: LN(cls) @ fc2 + softmax + argmax ----------
__global__ void k_final(const float* hbuf, const float* g, const float* bt,
                        const float* fw, const float* fb, float* outp){
  int b = blockIdx.x, t = threadIdx.x;
  __shared__ float red[4];
  __shared__ float sx[512];
  __shared__ float lg[4];
  const float* x = hbuf + ((long)b*8192+191)*512;
  float2 xv = *(const float2*)(x + t*2);
  float s = xv.x + xv.y;
  for (int off=32; off; off>>=1) s += __shfl_down(s,off,64);
  if ((t&63)==0) red[t>>6]=s;
  __syncthreads();
  float mean = (red[0]+red[1]+red[2]+red[3])*(1.f/512.f);
  __syncthreads();
  float d0 = xv.x-mean, d1 = xv.y-mean;
  float ssq = d0*d0 + d1*d1;
  for (int off=32; off; off>>=1) ssq += __shfl_down(ssq,off,64);
  if ((t&63)==0) red[t>>6]=ssq;
  __syncthreads();
  float rstd = rsqrtf((red[0]+red[1]+red[2]+red[3])*(1.f/512.f) + 1e-5f);
  sx[t*2]   = d0*rstd*g[t*2]   + bt[t*2];
  sx[t*2+1] = d1*rstd*g[t*2+1] + bt[t*2+1];
  __syncthreads();
  int c = t>>7, jj = t&127;
  float part = 0.f;
  for (int kk=jj; kk<512; kk+=128) part += sx[kk]*fw[(long)kk*2 + c];
  for (int off=1; off<64; off<<=1) part += __shfl_xor(part,off,64);
  if ((t&63)==0) lg[t>>6]=part;
  __syncthreads();
  if (t==0){
    float l0 = lg[0]+lg[1] + fb[0];
    float l1 = lg[2]+lg[3] + fb[1];
    float m = fmaxf(l0,l1);
    float e0 = __expf(l0-m), e1 = __expf(l1-m);
    float inv = 1.f/(e0+e1);
    outp[b*2+0]=l0; outp[b*2+1]=l1;
    outp[4+b*2+0]=e0*inv; outp[4+b*2+1]=e1*inv;
    outp[8+b]=(l1>l0) ? 1.f : 0.f;
  }
}

// ===================== host launch =====================
extern "C" void kernel_launch(void* const* d_in, const int* in_sizes, int n_in,
                              void* d_out, int out_size, void* d_ws, size_t ws_size,
                              hipStream_t stream){
  (void)in_sizes; (void)n_in; (void)out_size; (void)ws_size;
  const long TOK = (long)2*8192*512;
  float* W    = (float*)d_ws;
  float* rc   = W;                         // 64 floats
  float* h    = W + 64;
  float* q    = h + TOK;
  float* k    = q + TOK;
  float* v    = k + TOK;                   // dead after k_vt/k_conv -> op alias
  u16*  xlnb  = (u16*)(v + TOK);
  u16*  headsb= xlnb + (long)16384*512;
  u16*  wT    = headsb + (long)16384*512;  // 1,048,576 u16 capacity
  float* ql   = (float*)(wT + 1048576);
  float* kl   = ql + 262144;
  float* w3   = kl + 262144;
  float* a2   = w3 + 262144;
  float* z    = a2 + 1048576;
  float* z2   = z  + 1048576;
  float* xz   = z2 + 1048576;
  float* t1   = xz + 1048576;
  float* t2   = t1 + 1048576;
  u16*  vt    = (u16*)(t2 + 1048576);      // 16*64*8192 u16
  u16*  zwT   = vt + (long)16*64*8192;     // 16*64*256 u16
  float* op   = v;                         // 16*16*256*64 f32 = 16.78MB <= v
  float* ml   = t2;                        // 131072 f32, Newton done by then

  dim3 B(256);

  k_cls<<<dim3(2), B, 0, stream>>>((const float*)d_in[3], h);
  k_cvtT<<<dim3(16,32), B, 0, stream>>>((const float*)d_in[1], wT, 1024, 512);
  k_gemm<0><<<dim3(125,4), B, 0, stream>>>(d_in[0], wT, (const float*)d_in[2],
                                           h, nullptr,nullptr,nullptr, 16000,512,1024);

  for (int blk=0; blk<2; ++blk){
    const float* lng  = (const float*)d_in[blk?10:4];
    const float* lnb  = (const float*)d_in[blk?11:5];
    const float* qkvw = (const float*)d_in[blk?12:6];
    const float* outw = (const float*)d_in[blk?13:7];
    const float* outb = (const float*)d_in[blk?14:8];
    const float* cw   = (const float*)d_in[blk?15:9];

    k_ln<<<dim3(16384), B, 0, stream>>>(h, lng, lnb, xlnb);

    k_cvtT<<<dim3(48,16), B, 0, stream>>>(qkvw, wT, 512, 1536);
    k_gemm<1><<<dim3(128,12), B, 0, stream>>>(xlnb, wT, nullptr,
                                              nullptr, q,k,v, 16384,1536,512);

    k_landmark<<<dim3(256,16), dim3(64), 0, stream>>>(q, ql);
    k_landmark<<<dim3(256,16), dim3(64), 0, stream>>>(k, kl);

    k_vt<<<dim3(256,16), B, 0, stream>>>(v, vt);
    k_conv<<<dim3(64,16), B, 0, stream>>>(v, cw, headsb);

    k_a2<<<dim3(16,16), B, 0, stream>>>(ql, kl, a2);
    k_colrow<<<dim3(16), B, 0, stream>>>(a2, rc);
    k_denom<<<dim3(1), dim3(1), 0, stream>>>(rc, rc+32);
    k_z0<<<dim3(8,8,16), B, 0, stream>>>(a2, rc+32, z);

    for (int it=0; it<6; ++it){
      float* zin  = (it&1) ? z2 : z;
      float* zout = (it&1) ? z  : z2;
      k_mm256<<<dim3(4,4,16), B, 0, stream>>>(a2, zin, xz, t1, nullptr, 0.f,1.f,  7.f,-1.f, 256,256);
      k_mm256<<<dim3(4,4,16), B, 0, stream>>>(xz, t1, t2, nullptr, nullptr, 15.f,-1.f, 0.f,0.f, 256,256);
      k_mm256<<<dim3(4,4,16), B, 0, stream>>>(xz, t2, t1, nullptr, nullptr, 13.f,-1.f, 0.f,0.f, 256,256);
      k_mm256<<<dim3(4,4,16), B, 0, stream>>>(zin, t1, zout, nullptr, nullptr, 0.f,0.25f, 0.f,0.f, 256,256);
    }

    // a3: w3 = softmax(q_l @ k^T) @ v  (split-K 16 chunks of 512)
    k_flash2<0><<<dim3(4,16,16), B, 0, stream>>>(ql, k, vt, op, ml, nullptr,
                                                 512, 16384L, 524288L, 524288L, 8192);
    k_fcomb<<<dim3(16,16), B, 0, stream>>>(op, ml, w3);
    // zwT bf16 = (z @ w3)^T
    k_mm256<<<dim3(4,1,16), B, 0, stream>>>(z, w3, nullptr, nullptr, zwT, 0.f,1.f, 0.f,0.f, 64,256);
    // a1: headsb += softmax(q @ k_l^T) @ zw
    k_flash2<1><<<dim3(128,16,1), B, 0, stream>>>(q, kl, zwT, nullptr, nullptr, headsb,
                                                  256, 524288L, 16384L, 16384L, 256);

    k_cvtT<<<dim3(16,16), B, 0, stream>>>(outw, wT, 512, 512);
    k_gemm<2><<<dim3(128,4), B, 0, stream>>>(headsb, wT, outb,
                                             h, nullptr,nullptr,nullptr, 16384,512,512);
  }

  k_final<<<dim3(2), B, 0, stream>>>(h, (const float*)d_in[16], (const float*)d_in[17],
                                     (const float*)d_in[18], (const float*)d_in[19], (float*)d_out);
}